// Round 3
// baseline (428.352 us; speedup 1.0000x reference)
//
#include <hip/hip_runtime.h>

// ---------------------------------------------------------------------------
// SeqPairAttentionOutput on MI355X — round 3: 7 launches.
// B=1, L=512, D=1024, H=16, HW=64, PD=128.
// mega1 = [p2s-setup inline + p2s bf16-bias + weight transposes + ln1 + sbuf init]
// flash = [QK^T + bias(C-operand) + online softmax + PV + gate]
// o_w / mlp2 = split-K GEMMs finishing via fp32 atomicAdd into preinit buffers.
// ---------------------------------------------------------------------------

typedef __attribute__((ext_vector_type(8))) short bfrag;   // 8 bf16 (4 VGPRs)
typedef __attribute__((ext_vector_type(4))) float f32x4;
typedef unsigned short ushort_t;
typedef unsigned int u32;

#define AS1 __attribute__((address_space(1)))
#define AS3 __attribute__((address_space(3)))

__device__ __forceinline__ void gll16(const void* g, void* l) {
  __builtin_amdgcn_global_load_lds((const AS1 u32*)g, (AS3 u32*)l, 16, 0, 0);
}

__device__ __forceinline__ unsigned short f2b(float x) {
  union { float f; unsigned u; } a; a.f = x;
  unsigned r = a.u + 0x7fffu + ((a.u >> 16) & 1u);   // RNE
  return (unsigned short)(r >> 16);
}
__device__ __forceinline__ unsigned pack2(float a, float b) {
  return (unsigned)f2b(a) | ((unsigned)f2b(b) << 16);
}
__device__ __forceinline__ float b2f(ushort_t u) {
  union { float f; unsigned v; } a; a.v = ((unsigned)u) << 16; return a.f;
}

// ---------------------------------------------------------------------------
// workspace layout (bytes)
// ---------------------------------------------------------------------------
#define OFF_BIASH ((size_t)0)                        // bias bf16 [16][512][512] 8MB
#define OFF_Y     ((size_t)8388608)                  // y bf16 [512][1024] 1MB
#define OFF_QS    (OFF_Y    + (size_t)1048576)       // q bf16 [16][512][64] (scaled)
#define OFF_KS    (OFF_QS   + (size_t)1048576)
#define OFF_VT    (OFF_KS   + (size_t)1048576)       // v^T bf16 [16][64][512]
#define OFF_GATE  (OFF_VT   + (size_t)1048576)       // gate f32 [512][1024] 2MB
#define OFF_OG    (OFF_GATE + (size_t)2097152)       // gate*o bf16 [512][1024] 1MB
#define OFF_S     (OFF_OG   + (size_t)1048576)       // s f32 [512][1024] 2MB
#define OFF_HLN   (OFF_S    + (size_t)2097152)       // LN(s) bf16 1MB
#define OFF_H1    (OFF_HLN  + (size_t)1048576)       // h1 bf16 [512][4096] 4MB
#define OFF_WPG   (OFF_H1   + (size_t)4194304)       // [proj|g]^T bf16 [4096][1024] 8MB
#define OFF_WO    (OFF_WPG  + (size_t)8388608)       // o_w^T bf16 [1024][1024] 2MB
#define OFF_W1    (OFF_WO   + (size_t)2097152)       // w1^T bf16 [4096][1024] 8MB
#define OFF_W2    (OFF_W1   + (size_t)8388608)       // w2^T bf16 [1024][4096] 8MB

// ---------------------------------------------------------------------------
// transpose + cvt helper: W[K][N] -> Wt[N][K] bf16 (one 64x64 tile)
// ---------------------------------------------------------------------------
__device__ __forceinline__ void transp_tile(
    const float* __restrict__ W, ushort_t* __restrict__ Wt, int K, int N,
    int bx, int by, int tid, float* smem) {
  float (*tile)[65] = (float(*)[65])smem;
  int n0 = bx * 64, k0 = by * 64;
  int tr = tid >> 4, tc = (tid & 15) * 4;
#pragma unroll
  for (int i = 0; i < 4; i++) {
    int r = tr + i * 16;
    float4 v = *(const float4*)&W[(long)(k0 + r) * N + n0 + tc];
    tile[r][tc] = v.x; tile[r][tc + 1] = v.y; tile[r][tc + 2] = v.z; tile[r][tc + 3] = v.w;
  }
  __syncthreads();
  int nr = tid >> 2, kk = (tid & 3) * 16;
  ushort_t* dst = Wt + (long)(n0 + nr) * K + k0 + kk;
  uint4 q;
  q.x = pack2(tile[kk + 0][nr], tile[kk + 1][nr]);
  q.y = pack2(tile[kk + 2][nr], tile[kk + 3][nr]);
  q.z = pack2(tile[kk + 4][nr], tile[kk + 5][nr]);
  q.w = pack2(tile[kk + 6][nr], tile[kk + 7][nr]);
  *(uint4*)dst = q;
  uint4 q2;
  q2.x = pack2(tile[kk + 8][nr],  tile[kk + 9][nr]);
  q2.y = pack2(tile[kk + 10][nr], tile[kk + 11][nr]);
  q2.z = pack2(tile[kk + 12][nr], tile[kk + 13][nr]);
  q2.w = pack2(tile[kk + 14][nr], tile[kk + 15][nr]);
  *(uint4*)(dst + 8) = q2;
}

// ---------------------------------------------------------------------------
// mega1: block-ranged fusion of p2s / transposes / ln1+sbuf-init.
//   [0,16384)        p2s: 16 pairs/block, inline gw setup, bf16 bias out
//   [16384,19712)    weight transposes (5 sub-ranges)
//   [19712,20224)    ln1(seq)->ybf ; sbuf = seq + o_b
// ---------------------------------------------------------------------------
__global__ __launch_bounds__(256) void mega1(
    const float* __restrict__ pw,
    const float* __restrict__ p2s_g, const float* __restrict__ p2s_b,
    const float* __restrict__ p2s_w,
    const float* __restrict__ proj_w, const float* __restrict__ g_w,
    const float* __restrict__ o_w, const float* __restrict__ w1,
    const float* __restrict__ w2,
    const float* __restrict__ seq, const float* __restrict__ ln1_g,
    const float* __restrict__ ln1_b, const float* __restrict__ o_b,
    ushort_t* __restrict__ biasH, ushort_t* __restrict__ wpg,
    ushort_t* __restrict__ wo, ushort_t* __restrict__ w1t,
    ushort_t* __restrict__ w2t, ushort_t* __restrict__ ybf,
    float* __restrict__ sbuf) {
  __shared__ float smem[4528];
  const int id = blockIdx.x, t = threadIdx.x;

  if (id < 16384) {
    // ---- p2s ----
    float* gwt = smem;           // 16*132
    float* xs  = smem + 2112;    // 16*132
    float* cc  = smem + 4224;    // 32  (c1[16], c2[16])
    float* res = smem + 4256;    // 16*17

    // inline setup: gwt[h][f] = g[f]*w[f][h] (padded 132)
#pragma unroll
    for (int i = t; i < 2048; i += 256) {
      int h = i >> 7, f = i & 127;
      gwt[h * 132 + f] = p2s_g[f] * p2s_w[f * 16 + h];
    }
    if (t < 32) {
      int h = t & 15;
      const float* src = (t >> 4) ? p2s_b : p2s_g;
      float sum = 0.f;
      for (int f = 0; f < 128; f++) sum += src[f] * p2s_w[f * 16 + h];
      cc[t] = sum;
    }

    const long pair0 = (long)id * 16;
    const int p = t >> 4, h = t & 15, f0 = h * 8;
    const float* src = pw + pair0 * 128 + (long)t * 8;
    float4 x0 = *(const float4*)src;
    float4 x1 = *(const float4*)(src + 4);
    *(float4*)&xs[p * 132 + f0]     = x0;
    *(float4*)&xs[p * 132 + f0 + 4] = x1;

    float s  = x0.x + x0.y + x0.z + x0.w + x1.x + x1.y + x1.z + x1.w;
    float sq = x0.x*x0.x + x0.y*x0.y + x0.z*x0.z + x0.w*x0.w
             + x1.x*x1.x + x1.y*x1.y + x1.z*x1.z + x1.w*x1.w;
#pragma unroll
    for (int m = 1; m < 16; m <<= 1) { s += __shfl_xor(s, m); sq += __shfl_xor(sq, m); }
    float mu  = s * (1.f / 128.f);
    float var = sq * (1.f / 128.f) - mu * mu;
    float rs  = rsqrtf(var + 1e-5f);

    __syncthreads();

    float acc = 0.f;
#pragma unroll 8
    for (int f = 0; f < 128; f += 4) {
      float4 xv = *(const float4*)&xs[p * 132 + f];
      float4 wv = *(const float4*)&gwt[h * 132 + f];
      acc += xv.x * wv.x + xv.y * wv.y + xv.z * wv.z + xv.w * wv.w;
    }
    float val = rs * (acc - mu * cc[h]) + cc[16 + h];
    res[h * 17 + p] = val;
    __syncthreads();
    // transposed write: lanes 0..15 write consecutive pairs of one head plane
    int h2 = t >> 4, p2 = t & 15;
    biasH[(long)h2 * 262144 + pair0 + p2] = f2b(res[h2 * 17 + p2]);
  } else if (id < 19712) {
    int j = id - 16384;
    if (j < 768)       transp_tile(proj_w, wpg, 1024, 3072, j % 48, j / 48, t, smem);
    else if (j < 1024) { j -= 768;  transp_tile(g_w, wpg + (long)3072 * 1024, 1024, 1024, j % 16, j / 16, t, smem); }
    else if (j < 1280) { j -= 1024; transp_tile(o_w, wo, 1024, 1024, j % 16, j / 16, t, smem); }
    else if (j < 2304) { j -= 1280; transp_tile(w1, w1t, 1024, 4096, j % 64, j / 64, t, smem); }
    else               { j -= 2304; transp_tile(w2, w2t, 4096, 1024, j % 16, j / 16, t, smem); }
  } else {
    // ---- ln1 + sbuf init ----
    int row = id - 19712;
    long base = (long)row * 1024 + t * 4;
    float4 v = *(const float4*)(seq + base);
    float4 ob = *(const float4*)(o_b + t * 4);
    float4 sv; sv.x = v.x + ob.x; sv.y = v.y + ob.y; sv.z = v.z + ob.z; sv.w = v.w + ob.w;
    *(float4*)(sbuf + base) = sv;
    float s  = v.x + v.y + v.z + v.w;
    float sq = v.x*v.x + v.y*v.y + v.z*v.z + v.w*v.w;
#pragma unroll
    for (int k = 1; k < 64; k <<= 1) { s += __shfl_xor(s, k); sq += __shfl_xor(sq, k); }
    if ((t & 63) == 0) { smem[t >> 6] = s; smem[4 + (t >> 6)] = sq; }
    __syncthreads();
    s  = smem[0] + smem[1] + smem[2] + smem[3];
    sq = smem[4] + smem[5] + smem[6] + smem[7];
    float mu = s * (1.f / 1024.f);
    float rsd = rsqrtf(sq * (1.f / 1024.f) - mu * mu + 1e-5f);
    float4 gv = *(const float4*)(ln1_g + t * 4);
    float4 bv = *(const float4*)(ln1_b + t * 4);
    uint2 o;
    o.x = pack2((v.x - mu) * rsd * gv.x + bv.x, (v.y - mu) * rsd * gv.y + bv.y);
    o.y = pack2((v.z - mu) * rsd * gv.z + bv.z, (v.w - mu) * rsd * gv.w + bv.w);
    *(uint2*)(ybf + base) = o;
  }
}

// ---------------------------------------------------------------------------
// 64(M) x 128(N) MFMA GEMM, global_load_lds staging, Bt layout [N][K].
// EPI 3: relu(acc + bias1[ocol]) -> outH bf16
// EPI 6: proj+gate scatter (qs/ks/vt bf16, sigmoid gate fp32)
// EPI 7: split-K partial -> atomicAdd into outF (fp32)
// ---------------------------------------------------------------------------
template <int EPI>
__global__ __launch_bounds__(256) void gemm128(
    const ushort_t* __restrict__ A, const ushort_t* __restrict__ Bt,
    int lda, int ldb, int Ksplit,
    const float* __restrict__ bias1,
    float* __restrict__ outF, ushort_t* __restrict__ outH, int ldc,
    ushort_t* __restrict__ qs, ushort_t* __restrict__ ks,
    ushort_t* __restrict__ vt, float* __restrict__ gatebuf) {
  __shared__ ushort_t As[64 * 32];    // 4 KB
  __shared__ ushort_t Bs[128 * 32];   // 8 KB
  const int tid = threadIdx.x;
  const int w = tid >> 6, lane = tid & 63;
  const int ln = lane & 15, quad = lane >> 4;
  const int wm = w >> 1, wn = w & 1;
  const int m0 = blockIdx.y * 64, n0 = blockIdx.x * 128;
  const int z = blockIdx.z;
  const int Koff = (EPI == 7) ? z * Ksplit : 0;

  const ushort_t* ga  = A  + (long)(m0 + (tid >> 2)) * lda + Koff + (tid & 3) * 8;
  const ushort_t* gb0 = Bt + (long)(n0 + (tid >> 2)) * ldb + Koff + (tid & 3) * 8;
  const ushort_t* gb1 = gb0 + (long)64 * ldb;
  unsigned wofs = __builtin_amdgcn_readfirstlane(w * 1024);
  char* lA  = (char*)As + wofs;
  char* lB0 = (char*)Bs + wofs;
  char* lB1 = (char*)Bs + 4096 + wofs;

  f32x4 acc[2][4];
#pragma unroll
  for (int i = 0; i < 2; i++)
#pragma unroll
    for (int j = 0; j < 4; j++) acc[i][j] = (f32x4){0.f, 0.f, 0.f, 0.f};

  for (int k0 = 0; k0 < Ksplit; k0 += 32) {
    gll16(ga + k0, lA);
    gll16(gb0 + k0, lB0);
    gll16(gb1 + k0, lB1);
    __syncthreads();
    bfrag a0 = *(const bfrag*)&As[(wm * 32 + ln) * 32 + quad * 8];
    bfrag a1 = *(const bfrag*)&As[(wm * 32 + 16 + ln) * 32 + quad * 8];
#pragma unroll
    for (int bn = 0; bn < 4; bn++) {
      bfrag b = *(const bfrag*)&Bs[(wn * 64 + bn * 16 + ln) * 32 + quad * 8];
      acc[0][bn] = __builtin_amdgcn_mfma_f32_16x16x32_bf16(a0, b, acc[0][bn], 0, 0, 0);
      acc[1][bn] = __builtin_amdgcn_mfma_f32_16x16x32_bf16(a1, b, acc[1][bn], 0, 0, 0);
    }
    __syncthreads();
  }

#pragma unroll
  for (int am = 0; am < 2; am++) {
#pragma unroll
    for (int bn = 0; bn < 4; bn++) {
      int ocol = n0 + wn * 64 + bn * 16 + ln;
#pragma unroll
      for (int r = 0; r < 4; r++) {
        int orow = m0 + wm * 32 + am * 16 + quad * 4 + r;
        float v = acc[am][bn][r];
        if (EPI == 3) {
          v = fmaxf(v + bias1[ocol], 0.f);
          outH[(long)orow * ldc + ocol] = f2b(v);
        } else if (EPI == 6) {
          if (ocol < 3072) {
            int h = ocol / 192, j = ocol - h * 192;
            if (j < 64)       qs[((long)h * 512 + orow) * 64 + j] = f2b(v * 0.125f);
            else if (j < 128) ks[((long)h * 512 + orow) * 64 + (j - 64)] = f2b(v);
            else              vt[((long)h * 64 + (j - 128)) * 512 + orow] = f2b(v);
          } else {
            int gcol = ocol - 3072;
            float gv = v + bias1[gcol];
            gatebuf[(long)orow * 1024 + gcol] = 1.f / (1.f + __expf(-gv));
          }
        } else { // EPI 7
          atomicAdd(&outF[(long)orow * ldc + ocol], v);
        }
      }
    }
  }
}

// ---------------------------------------------------------------------------
// flash attention: one block = one head x 64 q-rows. 4 waves x 16 rows.
// S = Q K^T + bias (bias enters as MFMA C operand), online softmax,
// P->LDS->A-frag, O += P V, epilogue applies 1/l and gate -> og bf16.
// ---------------------------------------------------------------------------
__global__ __launch_bounds__(256) void flash_attn(
    const ushort_t* __restrict__ qs, const ushort_t* __restrict__ ks,
    const ushort_t* __restrict__ vt, const ushort_t* __restrict__ biasH,
    const float* __restrict__ gate, ushort_t* __restrict__ og) {
  __shared__ ushort_t Qs[64 * 72];
  __shared__ ushort_t Ks[64 * 72];
  __shared__ ushort_t Vs[64 * 72];
  __shared__ ushort_t Ps[64 * 72];
  const int tid = threadIdx.x;
  const int w = tid >> 6, lane = tid & 63, ln = lane & 15, quad = lane >> 4;
  const int h = blockIdx.x, q0 = blockIdx.y * 64;
  const int r = tid >> 2, c0 = (tid & 3) * 16;

  { const ushort_t* src = qs + ((long)(h * 512 + q0 + r)) * 64 + c0;
    *(uint4*)&Qs[r * 72 + c0]     = *(const uint4*)src;
    *(uint4*)&Qs[r * 72 + c0 + 8] = *(const uint4*)(src + 8); }

  float m_[4], l_[4];
  f32x4 Oacc[4];
#pragma unroll
  for (int i = 0; i < 4; i++) { m_[i] = -1e30f; l_[i] = 0.f; Oacc[i] = (f32x4){0.f,0.f,0.f,0.f}; }

  for (int kt = 0; kt < 8; kt++) {
    const int k0 = kt * 64;
    __syncthreads();   // protect Ks/Vs (covers Qs on first iter)
    { const ushort_t* srcK = ks + ((long)(h * 512 + k0 + r)) * 64 + c0;
      *(uint4*)&Ks[r * 72 + c0]     = *(const uint4*)srcK;
      *(uint4*)&Ks[r * 72 + c0 + 8] = *(const uint4*)(srcK + 8);
      const ushort_t* srcV = vt + ((long)(h * 64 + r)) * 512 + k0 + c0;
      *(uint4*)&Vs[r * 72 + c0]     = *(const uint4*)srcV;
      *(uint4*)&Vs[r * 72 + c0 + 8] = *(const uint4*)(srcV + 8); }

    // bias tile into C operand
    f32x4 acc[4];
    const ushort_t* bp = biasH + ((long)h * 512 + q0 + w * 16 + quad * 4) * 512 + k0 + ln;
#pragma unroll
    for (int t4 = 0; t4 < 4; t4++)
#pragma unroll
      for (int rr = 0; rr < 4; rr++)
        acc[t4][rr] = b2f(bp[(long)rr * 512 + t4 * 16]);

    __syncthreads();
#pragma unroll
    for (int s = 0; s < 2; s++) {
      bfrag a = *(const bfrag*)&Qs[(w * 16 + ln) * 72 + s * 32 + quad * 8];
#pragma unroll
      for (int t4 = 0; t4 < 4; t4++) {
        bfrag b = *(const bfrag*)&Ks[(t4 * 16 + ln) * 72 + s * 32 + quad * 8];
        acc[t4] = __builtin_amdgcn_mfma_f32_16x16x32_bf16(a, b, acc[t4], 0, 0, 0);
      }
    }

    // online softmax update (row stats: 16 lanes of same quad hold one row set)
    float mt[4];
#pragma unroll
    for (int rr = 0; rr < 4; rr++)
      mt[rr] = fmaxf(fmaxf(acc[0][rr], acc[1][rr]), fmaxf(acc[2][rr], acc[3][rr]));
#pragma unroll
    for (int xm = 1; xm < 16; xm <<= 1)
#pragma unroll
      for (int rr = 0; rr < 4; rr++) mt[rr] = fmaxf(mt[rr], __shfl_xor(mt[rr], xm));
    float al[4];
#pragma unroll
    for (int rr = 0; rr < 4; rr++) {
      float mn = fmaxf(m_[rr], mt[rr]);
      al[rr] = __expf(m_[rr] - mn);
      m_[rr] = mn;
    }
#pragma unroll
    for (int t4 = 0; t4 < 4; t4++)
#pragma unroll
      for (int rr = 0; rr < 4; rr++)
        acc[t4][rr] = __expf(acc[t4][rr] - m_[rr]);
    float rs[4];
#pragma unroll
    for (int rr = 0; rr < 4; rr++)
      rs[rr] = acc[0][rr] + acc[1][rr] + acc[2][rr] + acc[3][rr];
#pragma unroll
    for (int xm = 1; xm < 16; xm <<= 1)
#pragma unroll
      for (int rr = 0; rr < 4; rr++) rs[rr] += __shfl_xor(rs[rr], xm);
#pragma unroll
    for (int rr = 0; rr < 4; rr++) l_[rr] = l_[rr] * al[rr] + rs[rr];
#pragma unroll
    for (int t4 = 0; t4 < 4; t4++)
#pragma unroll
      for (int rr = 0; rr < 4; rr++) Oacc[t4][rr] *= al[rr];

    // P -> LDS (C-layout scatter)
#pragma unroll
    for (int t4 = 0; t4 < 4; t4++)
#pragma unroll
      for (int rr = 0; rr < 4; rr++)
        Ps[(w * 16 + quad * 4 + rr) * 72 + t4 * 16 + ln] = f2b(acc[t4][rr]);
    __syncthreads();

    // O += P V
#pragma unroll
    for (int s = 0; s < 2; s++) {
      bfrag a = *(const bfrag*)&Ps[(w * 16 + ln) * 72 + s * 32 + quad * 8];
#pragma unroll
      for (int t4 = 0; t4 < 4; t4++) {
        bfrag b = *(const bfrag*)&Vs[(t4 * 16 + ln) * 72 + s * 32 + quad * 8];
        Oacc[t4] = __builtin_amdgcn_mfma_f32_16x16x32_bf16(a, b, Oacc[t4], 0, 0, 0);
      }
    }
  }

  // epilogue: normalize, gate, store bf16
  float inv[4];
#pragma unroll
  for (int rr = 0; rr < 4; rr++) inv[rr] = 1.f / l_[rr];
#pragma unroll
  for (int t4 = 0; t4 < 4; t4++) {
#pragma unroll
    for (int rr = 0; rr < 4; rr++) {
      int grow = q0 + w * 16 + quad * 4 + rr;
      int gcol = h * 64 + t4 * 16 + ln;
      float gt = gate[(long)grow * 1024 + gcol];
      og[(long)grow * 1024 + gcol] = f2b(Oacc[t4][rr] * inv[rr] * gt);
    }
  }
}

// ---------------------------------------------------------------------------
// ln2: hln = LN(sbuf)*g+b (bf16); out = sbuf + b2 (fp32, pre-init for mlp2 atomics)
// ---------------------------------------------------------------------------
__global__ __launch_bounds__(256) void ln2(
    const float* __restrict__ sbuf, const float* __restrict__ g,
    const float* __restrict__ b, const float* __restrict__ b2,
    ushort_t* __restrict__ hln, float* __restrict__ out) {
  __shared__ float ps[8];
  int row = blockIdx.x, t = threadIdx.x;
  long base = (long)row * 1024 + t * 4;
  float4 v = *(const float4*)(sbuf + base);
  float4 b2v = *(const float4*)(b2 + t * 4);
  float4 ov; ov.x = v.x + b2v.x; ov.y = v.y + b2v.y; ov.z = v.z + b2v.z; ov.w = v.w + b2v.w;
  *(float4*)(out + base) = ov;
  float s  = v.x + v.y + v.z + v.w;
  float sq = v.x*v.x + v.y*v.y + v.z*v.z + v.w*v.w;
#pragma unroll
  for (int k = 1; k < 64; k <<= 1) { s += __shfl_xor(s, k); sq += __shfl_xor(sq, k); }
  if ((t & 63) == 0) { ps[t >> 6] = s; ps[4 + (t >> 6)] = sq; }
  __syncthreads();
  s  = ps[0] + ps[1] + ps[2] + ps[3];
  sq = ps[4] + ps[5] + ps[6] + ps[7];
  float mu = s * (1.f / 1024.f);
  float rsd = rsqrtf(sq * (1.f / 1024.f) - mu * mu + 1e-5f);
  float4 gv = *(const float4*)(g + t * 4);
  float4 bv = *(const float4*)(b + t * 4);
  uint2 o;
  o.x = pack2((v.x - mu) * rsd * gv.x + bv.x, (v.y - mu) * rsd * gv.y + bv.y);
  o.y = pack2((v.z - mu) * rsd * gv.z + bv.z, (v.w - mu) * rsd * gv.w + bv.w);
  *(uint2*)(hln + base) = o;
}

// ---------------------------------------------------------------------------
extern "C" void kernel_launch(void* const* d_in, const int* in_sizes, int n_in,
                              void* d_out, int out_size, void* d_ws, size_t ws_size,
                              hipStream_t stream) {
  const float* seq    = (const float*)d_in[0];
  const float* pw     = (const float*)d_in[1];
  const float* ln1_g  = (const float*)d_in[3];
  const float* ln1_b  = (const float*)d_in[4];
  const float* proj_w = (const float*)d_in[5];
  const float* g_w    = (const float*)d_in[6];
  const float* g_b    = (const float*)d_in[7];
  const float* o_w    = (const float*)d_in[8];
  const float* o_b    = (const float*)d_in[9];
  const float* p2s_g  = (const float*)d_in[10];
  const float* p2s_b  = (const float*)d_in[11];
  const float* p2s_w  = (const float*)d_in[12];
  const float* mlp_g  = (const float*)d_in[13];
  const float* mlp_bb = (const float*)d_in[14];
  const float* w1     = (const float*)d_in[15];
  const float* b1     = (const float*)d_in[16];
  const float* w2     = (const float*)d_in[17];
  const float* b2     = (const float*)d_in[18];
  float* out = (float*)d_out;
  char* ws = (char*)d_ws;

  ushort_t* biasH = (ushort_t*)(ws + OFF_BIASH);
  ushort_t* ybf   = (ushort_t*)(ws + OFF_Y);
  ushort_t* qs    = (ushort_t*)(ws + OFF_QS);
  ushort_t* ks    = (ushort_t*)(ws + OFF_KS);
  ushort_t* vt    = (ushort_t*)(ws + OFF_VT);
  float* gatebuf  = (float*)(ws + OFF_GATE);
  ushort_t* og    = (ushort_t*)(ws + OFF_OG);
  float* sbuf     = (float*)(ws + OFF_S);
  ushort_t* hln   = (ushort_t*)(ws + OFF_HLN);
  ushort_t* h1    = (ushort_t*)(ws + OFF_H1);
  ushort_t* wpg   = (ushort_t*)(ws + OFF_WPG);
  ushort_t* wo    = (ushort_t*)(ws + OFF_WO);
  ushort_t* w1t   = (ushort_t*)(ws + OFF_W1);
  ushort_t* w2t   = (ushort_t*)(ws + OFF_W2);

  // K1: p2s + transposes + ln1 + sbuf init
  mega1<<<20224, 256, 0, stream>>>(pw, p2s_g, p2s_b, p2s_w,
                                   proj_w, g_w, o_w, w1, w2,
                                   seq, ln1_g, ln1_b, o_b,
                                   biasH, wpg, wo, w1t, w2t, ybf, sbuf);
  // K2: merged proj+gate GEMM -> qkv scatter + sigmoid gate
  gemm128<6><<<dim3(32, 8, 1), 256, 0, stream>>>(ybf, wpg, 1024, 1024, 1024,
                                                 g_b, nullptr, nullptr, 0,
                                                 qs, ks, vt, gatebuf);
  // K3: flash attention (+bias, +gate) -> og bf16
  flash_attn<<<dim3(16, 8), 256, 0, stream>>>(qs, ks, vt, biasH, gatebuf, og);
  // K4: o_w GEMM split-K=4, atomicAdd into sbuf (= seq + o_b + og@o_w = s)
  gemm128<7><<<dim3(8, 8, 4), 256, 0, stream>>>(og, wo, 1024, 1024, 256,
                                                nullptr, sbuf, nullptr, 1024,
                                                nullptr, nullptr, nullptr, nullptr);
  // K5: hln = LN(s); out = s + b2
  ln2<<<512, 256, 0, stream>>>(sbuf, mlp_g, mlp_bb, b2, hln, out);
  // K6: h1 = relu(hln @ w1 + b1) bf16
  gemm128<3><<<dim3(32, 8, 1), 256, 0, stream>>>(hln, w1t, 1024, 1024, 1024,
                                                 b1, nullptr, h1, 4096,
                                                 nullptr, nullptr, nullptr, nullptr);
  // K7: mlp2 split-K=4, atomicAdd into out (= s + b2 + h1@w2)
  gemm128<7><<<dim3(8, 8, 4), 256, 0, stream>>>(h1, w2t, 4096, 4096, 1024,
                                                nullptr, out, nullptr, 1024,
                                                nullptr, nullptr, nullptr, nullptr);
}

// Round 4
// 368.655 us; speedup vs baseline: 1.1619x; 1.1619x over previous
//
#include <hip/hip_runtime.h>

// ---------------------------------------------------------------------------
// SeqPairAttentionOutput on MI355X — round 4: 7 launches.
// r4 changes: p2s uses MFMA (z bf16 -> 16x16x32, coalesced w staging);
// flash attention 32-row q-tiles (256 blocks) w/ cross-wave softmax.
// ---------------------------------------------------------------------------

typedef __attribute__((ext_vector_type(8))) short bfrag;   // 8 bf16 (4 VGPRs)
typedef __attribute__((ext_vector_type(4))) float f32x4;
typedef unsigned short ushort_t;
typedef unsigned int u32;

#define AS1 __attribute__((address_space(1)))
#define AS3 __attribute__((address_space(3)))

__device__ __forceinline__ void gll16(const void* g, void* l) {
  __builtin_amdgcn_global_load_lds((const AS1 u32*)g, (AS3 u32*)l, 16, 0, 0);
}

__device__ __forceinline__ unsigned short f2b(float x) {
  union { float f; unsigned u; } a; a.f = x;
  unsigned r = a.u + 0x7fffu + ((a.u >> 16) & 1u);   // RNE
  return (unsigned short)(r >> 16);
}
__device__ __forceinline__ unsigned pack2(float a, float b) {
  return (unsigned)f2b(a) | ((unsigned)f2b(b) << 16);
}
__device__ __forceinline__ float b2f(ushort_t u) {
  union { float f; unsigned v; } a; a.v = ((unsigned)u) << 16; return a.f;
}

// ---------------------------------------------------------------------------
// workspace layout (bytes)
// ---------------------------------------------------------------------------
#define OFF_BIASH ((size_t)0)                        // bias bf16 [16][512][512] 8MB
#define OFF_Y     ((size_t)8388608)                  // y bf16 [512][1024] 1MB
#define OFF_QS    (OFF_Y    + (size_t)1048576)       // q bf16 [16][512][64] (scaled)
#define OFF_KS    (OFF_QS   + (size_t)1048576)
#define OFF_VT    (OFF_KS   + (size_t)1048576)       // v^T bf16 [16][64][512]
#define OFF_GATE  (OFF_VT   + (size_t)1048576)       // gate f32 [512][1024] 2MB
#define OFF_OG    (OFF_GATE + (size_t)2097152)       // gate*o bf16 [512][1024] 1MB
#define OFF_S     (OFF_OG   + (size_t)1048576)       // s f32 [512][1024] 2MB
#define OFF_HLN   (OFF_S    + (size_t)2097152)       // LN(s) bf16 1MB
#define OFF_H1    (OFF_HLN  + (size_t)1048576)       // h1 bf16 [512][4096] 4MB
#define OFF_WPG   (OFF_H1   + (size_t)4194304)       // [proj|g]^T bf16 [4096][1024] 8MB
#define OFF_WO    (OFF_WPG  + (size_t)8388608)       // o_w^T bf16 [1024][1024] 2MB
#define OFF_W1    (OFF_WO   + (size_t)2097152)       // w1^T bf16 [4096][1024] 8MB
#define OFF_W2    (OFF_W1   + (size_t)8388608)       // w2^T bf16 [1024][4096] 8MB

// ---------------------------------------------------------------------------
// transpose + cvt helper: W[K][N] -> Wt[N][K] bf16 (one 64x64 tile)
// ---------------------------------------------------------------------------
__device__ __forceinline__ void transp_tile(
    const float* __restrict__ W, ushort_t* __restrict__ Wt, int K, int N,
    int bx, int by, int tid, float* smem) {
  float (*tile)[65] = (float(*)[65])smem;
  int n0 = bx * 64, k0 = by * 64;
  int tr = tid >> 4, tc = (tid & 15) * 4;
#pragma unroll
  for (int i = 0; i < 4; i++) {
    int r = tr + i * 16;
    float4 v = *(const float4*)&W[(long)(k0 + r) * N + n0 + tc];
    tile[r][tc] = v.x; tile[r][tc + 1] = v.y; tile[r][tc + 2] = v.z; tile[r][tc + 3] = v.w;
  }
  __syncthreads();
  int nr = tid >> 2, kk = (tid & 3) * 16;
  ushort_t* dst = Wt + (long)(n0 + nr) * K + k0 + kk;
  uint4 q;
  q.x = pack2(tile[kk + 0][nr], tile[kk + 1][nr]);
  q.y = pack2(tile[kk + 2][nr], tile[kk + 3][nr]);
  q.z = pack2(tile[kk + 4][nr], tile[kk + 5][nr]);
  q.w = pack2(tile[kk + 6][nr], tile[kk + 7][nr]);
  *(uint4*)dst = q;
  uint4 q2;
  q2.x = pack2(tile[kk + 8][nr],  tile[kk + 9][nr]);
  q2.y = pack2(tile[kk + 10][nr], tile[kk + 11][nr]);
  q2.z = pack2(tile[kk + 12][nr], tile[kk + 13][nr]);
  q2.w = pack2(tile[kk + 14][nr], tile[kk + 15][nr]);
  *(uint4*)(dst + 8) = q2;
}

// ---------------------------------------------------------------------------
// mega1: block-ranged fusion.
//   [0,4096)       p2s via MFMA: 64 pairs/block
//   [4096,7424)    weight transposes
//   [7424,7936)    ln1(seq)->ybf ; sbuf = seq + o_b
// ---------------------------------------------------------------------------
__global__ __launch_bounds__(256) void mega1(
    const float* __restrict__ pw,
    const float* __restrict__ p2s_g, const float* __restrict__ p2s_b,
    const float* __restrict__ p2s_w,
    const float* __restrict__ proj_w, const float* __restrict__ g_w,
    const float* __restrict__ o_w, const float* __restrict__ w1,
    const float* __restrict__ w2,
    const float* __restrict__ seq, const float* __restrict__ ln1_g,
    const float* __restrict__ ln1_b, const float* __restrict__ o_b,
    ushort_t* __restrict__ biasH, ushort_t* __restrict__ wpg,
    ushort_t* __restrict__ wo, ushort_t* __restrict__ w1t,
    ushort_t* __restrict__ w2t, ushort_t* __restrict__ ybf,
    float* __restrict__ sbuf) {
  __shared__ float smemF[5920];   // 23680 B, shared by all branches
  const int id = blockIdx.x, t = threadIdx.x;

  if (id < 4096) {
    // ---- p2s: 64 pairs, MFMA dot ----
    ushort_t* wb  = (ushort_t*)smemF;        // 2048 (B-frag layout)
    ushort_t* zsb = wb + 2048;               // 64 rows x 136 (A rows, +8 pad)
    ushort_t* res = zsb + 64 * 136;          // 16 heads x 68 pairs (pad 4)
    const int w = t >> 6, lane = t & 63, ln = lane & 15, quad = lane >> 4;
    const long pair0 = (long)id * 64;
    const int p = t >> 2, j = t & 3;         // thread: pair p, feature-quarter j

    // stage w coalesced -> bf16 B-frag layout:
    // wb[(chunk*64 + q2*16 + h)*8 + jj] = w[f= chunk*32+q2*8+jj][h]
#pragma unroll
    for (int i = t; i < 2048; i += 256) {
      int f = i >> 4, hh = i & 15;
      int chunk = f >> 5, q2 = (f >> 3) & 3, jj = f & 7;
      wb[(chunk * 64 + q2 * 16 + hh) * 8 + jj] = f2b(p2s_w[i]);
    }

    // load x (32 floats of pair p), stats over 4-lane group
    const float4* xsrc = (const float4*)(pw + (pair0 + p) * 128 + j * 32);
    float4 xv[8];
#pragma unroll
    for (int q = 0; q < 8; q++) xv[q] = xsrc[q];
    float s = 0.f, sq = 0.f;
#pragma unroll
    for (int q = 0; q < 8; q++) {
      s  += xv[q].x + xv[q].y + xv[q].z + xv[q].w;
      sq += xv[q].x*xv[q].x + xv[q].y*xv[q].y + xv[q].z*xv[q].z + xv[q].w*xv[q].w;
    }
    s  += __shfl_xor(s, 1);  s  += __shfl_xor(s, 2);
    sq += __shfl_xor(sq, 1); sq += __shfl_xor(sq, 2);
    float mu = s * (1.f / 128.f);
    float rs = rsqrtf(sq * (1.f / 128.f) - mu * mu + 1e-5f);

    const float4* g4 = (const float4*)(p2s_g + j * 32);
    const float4* b4 = (const float4*)(p2s_b + j * 32);
    uint4* zdst = (uint4*)&zsb[p * 136 + j * 32];
#pragma unroll
    for (int q = 0; q < 4; q++) {
      float4 x0 = xv[2*q], x1 = xv[2*q+1];
      float4 g0 = g4[2*q], g1 = g4[2*q+1];
      float4 b0 = b4[2*q], b1 = b4[2*q+1];
      uint4 o;
      o.x = pack2((x0.x-mu)*rs*g0.x + b0.x, (x0.y-mu)*rs*g0.y + b0.y);
      o.y = pack2((x0.z-mu)*rs*g0.z + b0.z, (x0.w-mu)*rs*g0.w + b0.w);
      o.z = pack2((x1.x-mu)*rs*g1.x + b1.x, (x1.y-mu)*rs*g1.y + b1.y);
      o.w = pack2((x1.z-mu)*rs*g1.z + b1.z, (x1.w-mu)*rs*g1.w + b1.w);
      zdst[q] = o;
    }
    __syncthreads();

    // wave w computes pairs [w*16, w*16+16) x 16 heads, K=128 via 4 MFMA
    f32x4 acc = (f32x4){0.f, 0.f, 0.f, 0.f};
#pragma unroll
    for (int chunk = 0; chunk < 4; chunk++) {
      bfrag a  = *(const bfrag*)&zsb[(w * 16 + ln) * 136 + chunk * 32 + quad * 8];
      bfrag bf = *(const bfrag*)&wb[(chunk * 64 + quad * 16 + ln) * 8];
      acc = __builtin_amdgcn_mfma_f32_16x16x32_bf16(a, bf, acc, 0, 0, 0);
    }
    // res[head=ln][pair] for coalesced global write
    *(uint2*)&res[ln * 68 + w * 16 + quad * 4] =
        (uint2){pack2(acc[0], acc[1]), pack2(acc[2], acc[3])};
    __syncthreads();
    {
      int hh = t >> 4, base = (t & 15) * 4;
      *(uint2*)&biasH[(long)hh * 262144 + pair0 + base] =
          *(const uint2*)&res[hh * 68 + base];
    }
  } else if (id < 7424) {
    int j = id - 4096;
    if (j < 768)       transp_tile(proj_w, wpg, 1024, 3072, j % 48, j / 48, t, smemF);
    else if (j < 1024) { j -= 768;  transp_tile(g_w, wpg + (long)3072 * 1024, 1024, 1024, j % 16, j / 16, t, smemF); }
    else if (j < 1280) { j -= 1024; transp_tile(o_w, wo, 1024, 1024, j % 16, j / 16, t, smemF); }
    else if (j < 2304) { j -= 1280; transp_tile(w1, w1t, 1024, 4096, j % 64, j / 64, t, smemF); }
    else               { j -= 2304; transp_tile(w2, w2t, 4096, 1024, j % 16, j / 16, t, smemF); }
  } else {
    // ---- ln1 + sbuf init ----
    int row = id - 7424;
    long base = (long)row * 1024 + t * 4;
    float4 v = *(const float4*)(seq + base);
    float4 ob = *(const float4*)(o_b + t * 4);
    float4 sv; sv.x = v.x + ob.x; sv.y = v.y + ob.y; sv.z = v.z + ob.z; sv.w = v.w + ob.w;
    *(float4*)(sbuf + base) = sv;
    float s  = v.x + v.y + v.z + v.w;
    float sq = v.x*v.x + v.y*v.y + v.z*v.z + v.w*v.w;
#pragma unroll
    for (int k = 1; k < 64; k <<= 1) { s += __shfl_xor(s, k); sq += __shfl_xor(sq, k); }
    if ((t & 63) == 0) { smemF[t >> 6] = s; smemF[4 + (t >> 6)] = sq; }
    __syncthreads();
    s  = smemF[0] + smemF[1] + smemF[2] + smemF[3];
    sq = smemF[4] + smemF[5] + smemF[6] + smemF[7];
    float mu = s * (1.f / 1024.f);
    float rsd = rsqrtf(sq * (1.f / 1024.f) - mu * mu + 1e-5f);
    float4 gv = *(const float4*)(ln1_g + t * 4);
    float4 bv = *(const float4*)(ln1_b + t * 4);
    uint2 o;
    o.x = pack2((v.x - mu) * rsd * gv.x + bv.x, (v.y - mu) * rsd * gv.y + bv.y);
    o.y = pack2((v.z - mu) * rsd * gv.z + bv.z, (v.w - mu) * rsd * gv.w + bv.w);
    *(uint2*)(ybf + base) = o;
  }
}

// ---------------------------------------------------------------------------
// 64(M) x 128(N) MFMA GEMM, global_load_lds staging, Bt layout [N][K].
// EPI 3: relu(acc + bias1[ocol]) -> outH bf16
// EPI 6: proj+gate scatter (qs/ks/vt bf16, sigmoid gate fp32)
// EPI 7: split-K partial -> atomicAdd into outF (fp32)
// ---------------------------------------------------------------------------
template <int EPI>
__global__ __launch_bounds__(256) void gemm128(
    const ushort_t* __restrict__ A, const ushort_t* __restrict__ Bt,
    int lda, int ldb, int Ksplit,
    const float* __restrict__ bias1,
    float* __restrict__ outF, ushort_t* __restrict__ outH, int ldc,
    ushort_t* __restrict__ qs, ushort_t* __restrict__ ks,
    ushort_t* __restrict__ vt, float* __restrict__ gatebuf) {
  __shared__ ushort_t As[64 * 32];    // 4 KB
  __shared__ ushort_t Bs[128 * 32];   // 8 KB
  const int tid = threadIdx.x;
  const int w = tid >> 6, lane = tid & 63;
  const int ln = lane & 15, quad = lane >> 4;
  const int wm = w >> 1, wn = w & 1;
  const int m0 = blockIdx.y * 64, n0 = blockIdx.x * 128;
  const int z = blockIdx.z;
  const int Koff = (EPI == 7) ? z * Ksplit : 0;

  const ushort_t* ga  = A  + (long)(m0 + (tid >> 2)) * lda + Koff + (tid & 3) * 8;
  const ushort_t* gb0 = Bt + (long)(n0 + (tid >> 2)) * ldb + Koff + (tid & 3) * 8;
  const ushort_t* gb1 = gb0 + (long)64 * ldb;
  unsigned wofs = __builtin_amdgcn_readfirstlane(w * 1024);
  char* lA  = (char*)As + wofs;
  char* lB0 = (char*)Bs + wofs;
  char* lB1 = (char*)Bs + 4096 + wofs;

  f32x4 acc[2][4];
#pragma unroll
  for (int i = 0; i < 2; i++)
#pragma unroll
    for (int j = 0; j < 4; j++) acc[i][j] = (f32x4){0.f, 0.f, 0.f, 0.f};

  for (int k0 = 0; k0 < Ksplit; k0 += 32) {
    gll16(ga + k0, lA);
    gll16(gb0 + k0, lB0);
    gll16(gb1 + k0, lB1);
    __syncthreads();
    bfrag a0 = *(const bfrag*)&As[(wm * 32 + ln) * 32 + quad * 8];
    bfrag a1 = *(const bfrag*)&As[(wm * 32 + 16 + ln) * 32 + quad * 8];
#pragma unroll
    for (int bn = 0; bn < 4; bn++) {
      bfrag b = *(const bfrag*)&Bs[(wn * 64 + bn * 16 + ln) * 32 + quad * 8];
      acc[0][bn] = __builtin_amdgcn_mfma_f32_16x16x32_bf16(a0, b, acc[0][bn], 0, 0, 0);
      acc[1][bn] = __builtin_amdgcn_mfma_f32_16x16x32_bf16(a1, b, acc[1][bn], 0, 0, 0);
    }
    __syncthreads();
  }

#pragma unroll
  for (int am = 0; am < 2; am++) {
#pragma unroll
    for (int bn = 0; bn < 4; bn++) {
      int ocol = n0 + wn * 64 + bn * 16 + ln;
#pragma unroll
      for (int r = 0; r < 4; r++) {
        int orow = m0 + wm * 32 + am * 16 + quad * 4 + r;
        float v = acc[am][bn][r];
        if (EPI == 3) {
          v = fmaxf(v + bias1[ocol], 0.f);
          outH[(long)orow * ldc + ocol] = f2b(v);
        } else if (EPI == 6) {
          if (ocol < 3072) {
            int h = ocol / 192, j = ocol - h * 192;
            if (j < 64)       qs[((long)h * 512 + orow) * 64 + j] = f2b(v * 0.125f);
            else if (j < 128) ks[((long)h * 512 + orow) * 64 + (j - 64)] = f2b(v);
            else              vt[((long)h * 64 + (j - 128)) * 512 + orow] = f2b(v);
          } else {
            int gcol = ocol - 3072;
            float gv = v + bias1[gcol];
            gatebuf[(long)orow * 1024 + gcol] = 1.f / (1.f + __expf(-gv));
          }
        } else { // EPI 7
          atomicAdd(&outF[(long)orow * ldc + ocol], v);
        }
      }
    }
  }
}

// ---------------------------------------------------------------------------
// flash attention: one block = one head x 32 q-rows, grid (16,16)=256 blocks.
// 4 waves: wm = w>>1 owns 16 rows, wn = w&1 owns 32-key half; cross-wave
// softmax stats via LDS. Bias enters as MFMA C operand.
// ---------------------------------------------------------------------------
__global__ __launch_bounds__(256) void flash_attn(
    const ushort_t* __restrict__ qs, const ushort_t* __restrict__ ks,
    const ushort_t* __restrict__ vt, const ushort_t* __restrict__ biasH,
    const float* __restrict__ gate, ushort_t* __restrict__ og) {
  __shared__ ushort_t Qs[32 * 72];
  __shared__ ushort_t Ks[64 * 72];
  __shared__ ushort_t Vs[64 * 72];
  __shared__ ushort_t Ps[32 * 72];
  __shared__ float redm[4][16];
  __shared__ float reds[4][16];
  const int tid = threadIdx.x;
  const int w = tid >> 6, lane = tid & 63, ln = lane & 15, quad = lane >> 4;
  const int wm = w >> 1, wn = w & 1;
  const int h = blockIdx.x, q0 = blockIdx.y * 32;

  {
    int r = tid >> 3, c0 = (tid & 7) * 8;
    *(uint4*)&Qs[r * 72 + c0] = *(const uint4*)(qs + ((long)(h * 512 + q0 + r)) * 64 + c0);
  }

  float m_[4], l_[4];
  f32x4 Oacc[2];
#pragma unroll
  for (int i = 0; i < 4; i++) { m_[i] = -1e30f; l_[i] = 0.f; }
  Oacc[0] = (f32x4){0.f,0.f,0.f,0.f};
  Oacc[1] = (f32x4){0.f,0.f,0.f,0.f};

  const int rkv = tid >> 2, ckv = (tid & 3) * 16;

  for (int kt = 0; kt < 8; kt++) {
    const int k0 = kt * 64;
    __syncthreads();
    { const ushort_t* srcK = ks + ((long)(h * 512 + k0 + rkv)) * 64 + ckv;
      *(uint4*)&Ks[rkv * 72 + ckv]     = *(const uint4*)srcK;
      *(uint4*)&Ks[rkv * 72 + ckv + 8] = *(const uint4*)(srcK + 8);
      const ushort_t* srcV = vt + ((long)(h * 64 + rkv)) * 512 + k0 + ckv;
      *(uint4*)&Vs[rkv * 72 + ckv]     = *(const uint4*)srcV;
      *(uint4*)&Vs[rkv * 72 + ckv + 8] = *(const uint4*)(srcV + 8); }

    // bias tile -> C operand
    f32x4 acc[2];
    const ushort_t* bp = biasH + ((long)h * 512 + q0 + wm * 16 + quad * 4) * 512
                         + k0 + wn * 32 + ln;
#pragma unroll
    for (int t4 = 0; t4 < 2; t4++)
#pragma unroll
      for (int rr = 0; rr < 4; rr++)
        acc[t4][rr] = b2f(bp[(long)rr * 512 + t4 * 16]);

    __syncthreads();
#pragma unroll
    for (int s = 0; s < 2; s++) {
      bfrag a = *(const bfrag*)&Qs[(wm * 16 + ln) * 72 + s * 32 + quad * 8];
#pragma unroll
      for (int t4 = 0; t4 < 2; t4++) {
        bfrag b = *(const bfrag*)&Ks[(wn * 32 + t4 * 16 + ln) * 72 + s * 32 + quad * 8];
        acc[t4] = __builtin_amdgcn_mfma_f32_16x16x32_bf16(a, b, acc[t4], 0, 0, 0);
      }
    }

    // local row max (this wave's 32 keys)
    float mt[4];
#pragma unroll
    for (int rr = 0; rr < 4; rr++) mt[rr] = fmaxf(acc[0][rr], acc[1][rr]);
#pragma unroll
    for (int xm = 1; xm < 16; xm <<= 1)
#pragma unroll
      for (int rr = 0; rr < 4; rr++) mt[rr] = fmaxf(mt[rr], __shfl_xor(mt[rr], xm));
    if (ln == 0)
#pragma unroll
      for (int rr = 0; rr < 4; rr++) redm[w][quad * 4 + rr] = mt[rr];
    __syncthreads();
#pragma unroll
    for (int rr = 0; rr < 4; rr++) mt[rr] = fmaxf(mt[rr], redm[w ^ 1][quad * 4 + rr]);

    float al[4];
#pragma unroll
    for (int rr = 0; rr < 4; rr++) {
      float mn = fmaxf(m_[rr], mt[rr]);
      al[rr] = __expf(m_[rr] - mn);
      m_[rr] = mn;
    }
#pragma unroll
    for (int t4 = 0; t4 < 2; t4++)
#pragma unroll
      for (int rr = 0; rr < 4; rr++)
        acc[t4][rr] = __expf(acc[t4][rr] - m_[rr]);

    float rsl[4];
#pragma unroll
    for (int rr = 0; rr < 4; rr++) rsl[rr] = acc[0][rr] + acc[1][rr];
#pragma unroll
    for (int xm = 1; xm < 16; xm <<= 1)
#pragma unroll
      for (int rr = 0; rr < 4; rr++) rsl[rr] += __shfl_xor(rsl[rr], xm);
    if (ln == 0)
#pragma unroll
      for (int rr = 0; rr < 4; rr++) reds[w][quad * 4 + rr] = rsl[rr];

    // P -> LDS (C-layout scatter), own 16x32 block
#pragma unroll
    for (int t4 = 0; t4 < 2; t4++)
#pragma unroll
      for (int rr = 0; rr < 4; rr++)
        Ps[(wm * 16 + quad * 4 + rr) * 72 + wn * 32 + t4 * 16 + ln] = f2b(acc[t4][rr]);
    __syncthreads();

#pragma unroll
    for (int rr = 0; rr < 4; rr++) {
      float rtot = rsl[rr] + reds[w ^ 1][quad * 4 + rr];
      l_[rr] = l_[rr] * al[rr] + rtot;
    }
#pragma unroll
    for (int t4 = 0; t4 < 2; t4++)
#pragma unroll
      for (int rr = 0; rr < 4; rr++) Oacc[t4][rr] *= al[rr];

    // O += P V  (contract over this tile's 64 keys)
#pragma unroll
    for (int s = 0; s < 2; s++) {
      bfrag a = *(const bfrag*)&Ps[(wm * 16 + ln) * 72 + s * 32 + quad * 8];
#pragma unroll
      for (int t4 = 0; t4 < 2; t4++) {
        bfrag b = *(const bfrag*)&Vs[(wn * 32 + t4 * 16 + ln) * 72 + s * 32 + quad * 8];
        Oacc[t4] = __builtin_amdgcn_mfma_f32_16x16x32_bf16(a, b, Oacc[t4], 0, 0, 0);
      }
    }
  }

  // epilogue: normalize, gate, store bf16
#pragma unroll
  for (int t4 = 0; t4 < 2; t4++) {
#pragma unroll
    for (int rr = 0; rr < 4; rr++) {
      int grow = q0 + wm * 16 + quad * 4 + rr;
      int gcol = h * 64 + wn * 32 + t4 * 16 + ln;
      float gt = gate[(long)grow * 1024 + gcol];
      og[(long)grow * 1024 + gcol] = f2b(Oacc[t4][rr] / l_[rr] * gt);
    }
  }
}

// ---------------------------------------------------------------------------
// ln2: hln = LN(sbuf)*g+b (bf16); out = sbuf + b2 (fp32, pre-init for mlp2 atomics)
// ---------------------------------------------------------------------------
__global__ __launch_bounds__(256) void ln2(
    const float* __restrict__ sbuf, const float* __restrict__ g,
    const float* __restrict__ b, const float* __restrict__ b2,
    ushort_t* __restrict__ hln, float* __restrict__ out) {
  __shared__ float ps[8];
  int row = blockIdx.x, t = threadIdx.x;
  long base = (long)row * 1024 + t * 4;
  float4 v = *(const float4*)(sbuf + base);
  float4 b2v = *(const float4*)(b2 + t * 4);
  float4 ov; ov.x = v.x + b2v.x; ov.y = v.y + b2v.y; ov.z = v.z + b2v.z; ov.w = v.w + b2v.w;
  *(float4*)(out + base) = ov;
  float s  = v.x + v.y + v.z + v.w;
  float sq = v.x*v.x + v.y*v.y + v.z*v.z + v.w*v.w;
#pragma unroll
  for (int k = 1; k < 64; k <<= 1) { s += __shfl_xor(s, k); sq += __shfl_xor(sq, k); }
  if ((t & 63) == 0) { ps[t >> 6] = s; ps[4 + (t >> 6)] = sq; }
  __syncthreads();
  s  = ps[0] + ps[1] + ps[2] + ps[3];
  sq = ps[4] + ps[5] + ps[6] + ps[7];
  float mu = s * (1.f / 1024.f);
  float rsd = rsqrtf(sq * (1.f / 1024.f) - mu * mu + 1e-5f);
  float4 gv = *(const float4*)(g + t * 4);
  float4 bv = *(const float4*)(b + t * 4);
  uint2 o;
  o.x = pack2((v.x - mu) * rsd * gv.x + bv.x, (v.y - mu) * rsd * gv.y + bv.y);
  o.y = pack2((v.z - mu) * rsd * gv.z + bv.z, (v.w - mu) * rsd * gv.w + bv.w);
  *(uint2*)(hln + base) = o;
}

// ---------------------------------------------------------------------------
extern "C" void kernel_launch(void* const* d_in, const int* in_sizes, int n_in,
                              void* d_out, int out_size, void* d_ws, size_t ws_size,
                              hipStream_t stream) {
  const float* seq    = (const float*)d_in[0];
  const float* pw     = (const float*)d_in[1];
  const float* ln1_g  = (const float*)d_in[3];
  const float* ln1_b  = (const float*)d_in[4];
  const float* proj_w = (const float*)d_in[5];
  const float* g_w    = (const float*)d_in[6];
  const float* g_b    = (const float*)d_in[7];
  const float* o_w    = (const float*)d_in[8];
  const float* o_b    = (const float*)d_in[9];
  const float* p2s_g  = (const float*)d_in[10];
  const float* p2s_b  = (const float*)d_in[11];
  const float* p2s_w  = (const float*)d_in[12];
  const float* mlp_g  = (const float*)d_in[13];
  const float* mlp_bb = (const float*)d_in[14];
  const float* w1     = (const float*)d_in[15];
  const float* b1     = (const float*)d_in[16];
  const float* w2     = (const float*)d_in[17];
  const float* b2     = (const float*)d_in[18];
  float* out = (float*)d_out;
  char* ws = (char*)d_ws;

  ushort_t* biasH = (ushort_t*)(ws + OFF_BIASH);
  ushort_t* ybf   = (ushort_t*)(ws + OFF_Y);
  ushort_t* qs    = (ushort_t*)(ws + OFF_QS);
  ushort_t* ks    = (ushort_t*)(ws + OFF_KS);
  ushort_t* vt    = (ushort_t*)(ws + OFF_VT);
  float* gatebuf  = (float*)(ws + OFF_GATE);
  ushort_t* og    = (ushort_t*)(ws + OFF_OG);
  float* sbuf     = (float*)(ws + OFF_S);
  ushort_t* hln   = (ushort_t*)(ws + OFF_HLN);
  ushort_t* h1    = (ushort_t*)(ws + OFF_H1);
  ushort_t* wpg   = (ushort_t*)(ws + OFF_WPG);
  ushort_t* wo    = (ushort_t*)(ws + OFF_WO);
  ushort_t* w1t   = (ushort_t*)(ws + OFF_W1);
  ushort_t* w2t   = (ushort_t*)(ws + OFF_W2);

  // K1: p2s(MFMA) + transposes + ln1 + sbuf init
  mega1<<<7936, 256, 0, stream>>>(pw, p2s_g, p2s_b, p2s_w,
                                  proj_w, g_w, o_w, w1, w2,
                                  seq, ln1_g, ln1_b, o_b,
                                  biasH, wpg, wo, w1t, w2t, ybf, sbuf);
  // K2: merged proj+gate GEMM -> qkv scatter + sigmoid gate
  gemm128<6><<<dim3(32, 8, 1), 256, 0, stream>>>(ybf, wpg, 1024, 1024, 1024,
                                                 g_b, nullptr, nullptr, 0,
                                                 qs, ks, vt, gatebuf);
  // K3: flash attention (+bias, +gate) -> og bf16
  flash_attn<<<dim3(16, 16), 256, 0, stream>>>(qs, ks, vt, biasH, gatebuf, og);
  // K4: o_w GEMM split-K=4, atomicAdd into sbuf (= seq + o_b + og@o_w = s)
  gemm128<7><<<dim3(8, 8, 4), 256, 0, stream>>>(og, wo, 1024, 1024, 256,
                                                nullptr, sbuf, nullptr, 1024,
                                                nullptr, nullptr, nullptr, nullptr);
  // K5: hln = LN(s); out = s + b2
  ln2<<<512, 256, 0, stream>>>(sbuf, mlp_g, mlp_bb, b2, hln, out);
  // K6: h1 = relu(hln @ w1 + b1) bf16
  gemm128<3><<<dim3(32, 8, 1), 256, 0, stream>>>(hln, w1t, 1024, 1024, 1024,
                                                 b1, nullptr, h1, 4096,
                                                 nullptr, nullptr, nullptr, nullptr);
  // K7: mlp2 split-K=4, atomicAdd into out (= s + b2 + h1@w2)
  gemm128<7><<<dim3(8, 8, 4), 256, 0, stream>>>(h1, w2t, 4096, 4096, 1024,
                                                nullptr, out, nullptr, 1024,
                                                nullptr, nullptr, nullptr, nullptr);
}

// Round 5
// 326.859 us; speedup vs baseline: 1.3105x; 1.1279x over previous
//
#include <hip/hip_runtime.h>

// ---------------------------------------------------------------------------
// SeqPairAttentionOutput on MI355X — round 5: 7 launches.
// r5: gemm64 dbuf gll16 (1 barrier/iter, 512-block grids = 2 blocks/CU);
// p2s 64B-line comb loads + nontemporal; flash wave-private softmax w/ end merge.
// ---------------------------------------------------------------------------

typedef __attribute__((ext_vector_type(8))) short bfrag;   // 8 bf16 (4 VGPRs)
typedef __attribute__((ext_vector_type(4))) float f32x4;
typedef unsigned short ushort_t;
typedef unsigned int u32;

#define AS1 __attribute__((address_space(1)))
#define AS3 __attribute__((address_space(3)))

__device__ __forceinline__ void gll16(const void* g, void* l) {
  __builtin_amdgcn_global_load_lds((const AS1 u32*)g, (AS3 u32*)l, 16, 0, 0);
}

__device__ __forceinline__ unsigned short f2b(float x) {
  union { float f; unsigned u; } a; a.f = x;
  unsigned r = a.u + 0x7fffu + ((a.u >> 16) & 1u);   // RNE
  return (unsigned short)(r >> 16);
}
__device__ __forceinline__ unsigned pack2(float a, float b) {
  return (unsigned)f2b(a) | ((unsigned)f2b(b) << 16);
}
__device__ __forceinline__ float b2f(ushort_t u) {
  union { float f; unsigned v; } a; a.v = ((unsigned)u) << 16; return a.f;
}

// workspace layout (bytes)
#define OFF_BIASH ((size_t)0)                        // bias bf16 [16][512][512] 8MB
#define OFF_Y     ((size_t)8388608)                  // y bf16 [512][1024] 1MB
#define OFF_QS    (OFF_Y    + (size_t)1048576)
#define OFF_KS    (OFF_QS   + (size_t)1048576)
#define OFF_VT    (OFF_KS   + (size_t)1048576)       // v^T bf16 [16][64][512]
#define OFF_GATE  (OFF_VT   + (size_t)1048576)       // gate f32 [512][1024] 2MB
#define OFF_OG    (OFF_GATE + (size_t)2097152)       // gate*o bf16 1MB
#define OFF_S     (OFF_OG   + (size_t)1048576)       // s f32 2MB
#define OFF_HLN   (OFF_S    + (size_t)2097152)       // LN(s) bf16 1MB
#define OFF_H1    (OFF_HLN  + (size_t)1048576)       // h1 bf16 [512][4096] 4MB
#define OFF_WPG   (OFF_H1   + (size_t)4194304)       // [proj|g]^T bf16 [4096][1024] 8MB
#define OFF_WO    (OFF_WPG  + (size_t)8388608)       // o_w^T bf16 2MB
#define OFF_W1    (OFF_WO   + (size_t)2097152)       // w1^T bf16 8MB
#define OFF_W2    (OFF_W1   + (size_t)8388608)       // w2^T bf16 8MB

// ---------------------------------------------------------------------------
// transpose + cvt helper: W[K][N] -> Wt[N][K] bf16 (one 64x64 tile)
// ---------------------------------------------------------------------------
__device__ __forceinline__ void transp_tile(
    const float* __restrict__ W, ushort_t* __restrict__ Wt, int K, int N,
    int bx, int by, int tid, float* smem) {
  float (*tile)[65] = (float(*)[65])smem;
  int n0 = bx * 64, k0 = by * 64;
  int tr = tid >> 4, tc = (tid & 15) * 4;
#pragma unroll
  for (int i = 0; i < 4; i++) {
    int r = tr + i * 16;
    f32x4 v = __builtin_nontemporal_load(
        (const f32x4*)&W[(long)(k0 + r) * N + n0 + tc]);
    tile[r][tc] = v.x; tile[r][tc + 1] = v.y; tile[r][tc + 2] = v.z; tile[r][tc + 3] = v.w;
  }
  __syncthreads();
  int nr = tid >> 2, kk = (tid & 3) * 16;
  ushort_t* dst = Wt + (long)(n0 + nr) * K + k0 + kk;
  uint4 q;
  q.x = pack2(tile[kk + 0][nr], tile[kk + 1][nr]);
  q.y = pack2(tile[kk + 2][nr], tile[kk + 3][nr]);
  q.z = pack2(tile[kk + 4][nr], tile[kk + 5][nr]);
  q.w = pack2(tile[kk + 6][nr], tile[kk + 7][nr]);
  *(uint4*)dst = q;
  uint4 q2;
  q2.x = pack2(tile[kk + 8][nr],  tile[kk + 9][nr]);
  q2.y = pack2(tile[kk + 10][nr], tile[kk + 11][nr]);
  q2.z = pack2(tile[kk + 12][nr], tile[kk + 13][nr]);
  q2.w = pack2(tile[kk + 14][nr], tile[kk + 15][nr]);
  *(uint4*)(dst + 8) = q2;
}

// ---------------------------------------------------------------------------
// mega1: [0,4096) p2s MFMA | [4096,7424) transposes | [7424,7936) ln1+sbuf
// ---------------------------------------------------------------------------
__global__ __launch_bounds__(256) void mega1(
    const float* __restrict__ pw,
    const float* __restrict__ p2s_g, const float* __restrict__ p2s_b,
    const float* __restrict__ p2s_w,
    const float* __restrict__ proj_w, const float* __restrict__ g_w,
    const float* __restrict__ o_w, const float* __restrict__ w1,
    const float* __restrict__ w2,
    const float* __restrict__ seq, const float* __restrict__ ln1_g,
    const float* __restrict__ ln1_b, const float* __restrict__ o_b,
    ushort_t* __restrict__ biasH, ushort_t* __restrict__ wpg,
    ushort_t* __restrict__ wo, ushort_t* __restrict__ w1t,
    ushort_t* __restrict__ w2t, ushort_t* __restrict__ ybf,
    float* __restrict__ sbuf) {
  __shared__ float smemF[5920];
  const int id = blockIdx.x, t = threadIdx.x;

  if (id < 4096) {
    // ---- p2s: 64 pairs/block, MFMA dot ----
    ushort_t* wb  = (ushort_t*)smemF;        // 2048
    ushort_t* zsb = wb + 2048;               // 64 x 136
    ushort_t* res = zsb + 64 * 136;          // 16 x 68
    const int w = t >> 6, lane = t & 63, ln = lane & 15, quad = lane >> 4;
    const long pair0 = (long)id * 64;
    const int p = w * 16 + (lane >> 2);      // local pair 0..63
    const int j = lane & 3;                  // quarter

    // stage w coalesced -> bf16 B-frag layout
#pragma unroll
    for (int i = t; i < 2048; i += 256) {
      int f = i >> 4, hh = i & 15;
      int chunk = f >> 5, q2 = (f >> 3) & 3, jj = f & 7;
      wb[(chunk * 64 + q2 * 16 + hh) * 8 + jj] = f2b(p2s_w[i]);
    }

    // x comb loads: lane j reads floats {j*4 + q*16 .. +4}, 64B line per 4 lanes
    const float* xbase = pw + (pair0 + p) * 128 + j * 4;
    f32x4 xv[8];
#pragma unroll
    for (int q = 0; q < 8; q++)
      xv[q] = __builtin_nontemporal_load((const f32x4*)(xbase + q * 16));
    float s = 0.f, sq = 0.f;
#pragma unroll
    for (int q = 0; q < 8; q++) {
      s  += xv[q].x + xv[q].y + xv[q].z + xv[q].w;
      sq += xv[q].x*xv[q].x + xv[q].y*xv[q].y + xv[q].z*xv[q].z + xv[q].w*xv[q].w;
    }
    s += __shfl_xor(s, 1); s += __shfl_xor(s, 2);
    sq += __shfl_xor(sq, 1); sq += __shfl_xor(sq, 2);
    float mu = s * (1.f / 128.f);
    float rs = rsqrtf(sq * (1.f / 128.f) - mu * mu + 1e-5f);

#pragma unroll
    for (int q = 0; q < 8; q++) {
      f32x4 gv = *(const f32x4*)(p2s_g + j * 4 + q * 16);
      f32x4 bv = *(const f32x4*)(p2s_b + j * 4 + q * 16);
      uint2 o;
      o.x = pack2((xv[q].x - mu) * rs * gv.x + bv.x, (xv[q].y - mu) * rs * gv.y + bv.y);
      o.y = pack2((xv[q].z - mu) * rs * gv.z + bv.z, (xv[q].w - mu) * rs * gv.w + bv.w);
      *(uint2*)&zsb[p * 136 + q * 16 + j * 4] = o;
    }
    __syncthreads();

    // wave w: pairs [w*16, w*16+16) x 16 heads, K=128 via 4 MFMA
    f32x4 acc = (f32x4){0.f, 0.f, 0.f, 0.f};
#pragma unroll
    for (int chunk = 0; chunk < 4; chunk++) {
      bfrag a  = *(const bfrag*)&zsb[(w * 16 + ln) * 136 + chunk * 32 + quad * 8];
      bfrag bf = *(const bfrag*)&wb[(chunk * 64 + quad * 16 + ln) * 8];
      acc = __builtin_amdgcn_mfma_f32_16x16x32_bf16(a, bf, acc, 0, 0, 0);
    }
    *(uint2*)&res[ln * 68 + w * 16 + quad * 4] =
        (uint2){pack2(acc[0], acc[1]), pack2(acc[2], acc[3])};
    __syncthreads();
    {
      int hh = t >> 4, base = (t & 15) * 4;
      *(uint2*)&biasH[(long)hh * 262144 + pair0 + base] =
          *(const uint2*)&res[hh * 68 + base];
    }
  } else if (id < 7424) {
    int j = id - 4096;
    if (j < 768)       transp_tile(proj_w, wpg, 1024, 3072, j % 48, j / 48, t, smemF);
    else if (j < 1024) { j -= 768;  transp_tile(g_w, wpg + (long)3072 * 1024, 1024, 1024, j % 16, j / 16, t, smemF); }
    else if (j < 1280) { j -= 1024; transp_tile(o_w, wo, 1024, 1024, j % 16, j / 16, t, smemF); }
    else if (j < 2304) { j -= 1280; transp_tile(w1, w1t, 1024, 4096, j % 64, j / 64, t, smemF); }
    else               { j -= 2304; transp_tile(w2, w2t, 4096, 1024, j % 16, j / 16, t, smemF); }
  } else {
    // ---- ln1 + sbuf init ----
    int row = id - 7424;
    long base = (long)row * 1024 + t * 4;
    float4 v = *(const float4*)(seq + base);
    float4 ob = *(const float4*)(o_b + t * 4);
    float4 sv; sv.x = v.x + ob.x; sv.y = v.y + ob.y; sv.z = v.z + ob.z; sv.w = v.w + ob.w;
    *(float4*)(sbuf + base) = sv;
    float s  = v.x + v.y + v.z + v.w;
    float sq = v.x*v.x + v.y*v.y + v.z*v.z + v.w*v.w;
#pragma unroll
    for (int k = 1; k < 64; k <<= 1) { s += __shfl_xor(s, k); sq += __shfl_xor(sq, k); }
    if ((t & 63) == 0) { smemF[t >> 6] = s; smemF[4 + (t >> 6)] = sq; }
    __syncthreads();
    s  = smemF[0] + smemF[1] + smemF[2] + smemF[3];
    sq = smemF[4] + smemF[5] + smemF[6] + smemF[7];
    float mu = s * (1.f / 1024.f);
    float rsd = rsqrtf(sq * (1.f / 1024.f) - mu * mu + 1e-5f);
    float4 gv = *(const float4*)(ln1_g + t * 4);
    float4 bv = *(const float4*)(ln1_b + t * 4);
    uint2 o;
    o.x = pack2((v.x - mu) * rsd * gv.x + bv.x, (v.y - mu) * rsd * gv.y + bv.y);
    o.y = pack2((v.z - mu) * rsd * gv.z + bv.z, (v.w - mu) * rsd * gv.w + bv.w);
    *(uint2*)(ybf + base) = o;
  }
}

// ---------------------------------------------------------------------------
// gemm64: 64x64 tile, double-buffered gll16 staging, 1 barrier/K-iter.
// 4 waves 2x2, each 32x32 (2 a-frag x 2 b-frag = 4 MFMA / K-32).
// EPI 3: relu(acc+bias1)->bf16 | EPI 6: qkv/gate scatter | EPI 7: atomicAdd f32
// ---------------------------------------------------------------------------
template <int EPI>
__global__ __launch_bounds__(256) void gemm64(
    const ushort_t* __restrict__ A, const ushort_t* __restrict__ Bt,
    int lda, int ldb, int Ksplit,
    const float* __restrict__ bias1,
    float* __restrict__ outF, ushort_t* __restrict__ outH, int ldc,
    ushort_t* __restrict__ qs, ushort_t* __restrict__ ks,
    ushort_t* __restrict__ vt, float* __restrict__ gatebuf) {
  __shared__ ushort_t As[2][64 * 32];   // 4 KB each
  __shared__ ushort_t Bs[2][64 * 32];
  const int tid = threadIdx.x;
  const int w = tid >> 6, lane = tid & 63;
  const int ln = lane & 15, quad = lane >> 4;
  const int wm = w >> 1, wn = w & 1;
  const int m0 = blockIdx.y * 64, n0 = blockIdx.x * 64;
  const int z = blockIdx.z;
  const int Koff = (EPI == 7) ? z * Ksplit : 0;

  const ushort_t* ga = A  + (long)(m0 + (tid >> 2)) * lda + Koff + (tid & 3) * 8;
  const ushort_t* gb = Bt + (long)(n0 + (tid >> 2)) * ldb + Koff + (tid & 3) * 8;
  unsigned wofs = __builtin_amdgcn_readfirstlane(w * 1024);
  char* lA[2] = {(char*)&As[0][0] + wofs, (char*)&As[1][0] + wofs};
  char* lB[2] = {(char*)&Bs[0][0] + wofs, (char*)&Bs[1][0] + wofs};

  f32x4 acc[2][2];
#pragma unroll
  for (int i = 0; i < 2; i++)
#pragma unroll
    for (int jj = 0; jj < 2; jj++) acc[i][jj] = (f32x4){0.f, 0.f, 0.f, 0.f};

  gll16(ga, lA[0]);
  gll16(gb, lB[0]);
  int buf = 0;
  for (int k0 = 0; k0 < Ksplit; k0 += 32) {
    __syncthreads();                       // tile(k0) staged; prev reads drained
    if (k0 + 32 < Ksplit) {                // prefetch next into other buffer
      gll16(ga + k0 + 32, lA[buf ^ 1]);
      gll16(gb + k0 + 32, lB[buf ^ 1]);
    }
    const ushort_t* Ab = &As[buf][0];
    const ushort_t* Bb = &Bs[buf][0];
    bfrag a0 = *(const bfrag*)&Ab[(wm * 32 + ln) * 32 + quad * 8];
    bfrag a1 = *(const bfrag*)&Ab[(wm * 32 + 16 + ln) * 32 + quad * 8];
    bfrag b0 = *(const bfrag*)&Bb[(wn * 32 + ln) * 32 + quad * 8];
    bfrag b1 = *(const bfrag*)&Bb[(wn * 32 + 16 + ln) * 32 + quad * 8];
    acc[0][0] = __builtin_amdgcn_mfma_f32_16x16x32_bf16(a0, b0, acc[0][0], 0, 0, 0);
    acc[0][1] = __builtin_amdgcn_mfma_f32_16x16x32_bf16(a0, b1, acc[0][1], 0, 0, 0);
    acc[1][0] = __builtin_amdgcn_mfma_f32_16x16x32_bf16(a1, b0, acc[1][0], 0, 0, 0);
    acc[1][1] = __builtin_amdgcn_mfma_f32_16x16x32_bf16(a1, b1, acc[1][1], 0, 0, 0);
    buf ^= 1;
  }

#pragma unroll
  for (int am = 0; am < 2; am++) {
#pragma unroll
    for (int bn = 0; bn < 2; bn++) {
      int ocol = n0 + wn * 32 + bn * 16 + ln;
#pragma unroll
      for (int r = 0; r < 4; r++) {
        int orow = m0 + wm * 32 + am * 16 + quad * 4 + r;
        float v = acc[am][bn][r];
        if (EPI == 3) {
          v = fmaxf(v + bias1[ocol], 0.f);
          outH[(long)orow * ldc + ocol] = f2b(v);
        } else if (EPI == 6) {
          if (ocol < 3072) {
            int h = ocol / 192, jq = ocol - h * 192;
            if (jq < 64)       qs[((long)h * 512 + orow) * 64 + jq] = f2b(v * 0.125f);
            else if (jq < 128) ks[((long)h * 512 + orow) * 64 + (jq - 64)] = f2b(v);
            else               vt[((long)h * 64 + (jq - 128)) * 512 + orow] = f2b(v);
          } else {
            int gcol = ocol - 3072;
            float gv = v + bias1[gcol];
            gatebuf[(long)orow * 1024 + gcol] = 1.f / (1.f + __expf(-gv));
          }
        } else { // EPI 7
          atomicAdd(&outF[(long)orow * ldc + ocol], v);
        }
      }
    }
  }
}

// ---------------------------------------------------------------------------
// flash attention: block = head x 32 q-rows, 4 waves (wm rows x wn key-half).
// Wave-private online softmax across its 32-key columns; merge once at end.
// 2 barriers/tile. Bias enters as MFMA C operand.
// ---------------------------------------------------------------------------
__global__ __launch_bounds__(256) void flash_attn(
    const ushort_t* __restrict__ qs, const ushort_t* __restrict__ ks,
    const ushort_t* __restrict__ vt, const ushort_t* __restrict__ biasH,
    const float* __restrict__ gate, ushort_t* __restrict__ og) {
  __shared__ ushort_t Qs[32 * 72];
  __shared__ ushort_t Ks[64 * 72];
  __shared__ ushort_t Vs[64 * 72];
  __shared__ ushort_t Ps[4][16 * 40];
  const int tid = threadIdx.x;
  const int w = tid >> 6, lane = tid & 63, ln = lane & 15, quad = lane >> 4;
  const int wm = w >> 1, wn = w & 1;
  const int h = blockIdx.x, q0 = blockIdx.y * 32;

  { int r = tid >> 3, c = (tid & 7) * 8;
    *(uint4*)&Qs[r * 72 + c] = *(const uint4*)(qs + ((long)(h * 512 + q0 + r)) * 64 + c); }

  float m_[4], l_[4];
  f32x4 Oacc[4];
#pragma unroll
  for (int i = 0; i < 4; i++) { m_[i] = -1e30f; l_[i] = 0.f; Oacc[i] = (f32x4){0.f,0.f,0.f,0.f}; }

  const int rkv = tid >> 2, ckv = (tid & 3) * 16;

  for (int kt = 0; kt < 8; kt++) {
    const int k0 = kt * 64;
    __syncthreads();                    // safe to overwrite K/V (covers Qs 1st iter)
    { const ushort_t* sk = ks + ((long)(h * 512 + k0 + rkv)) * 64 + ckv;
      *(uint4*)&Ks[rkv * 72 + ckv]     = *(const uint4*)sk;
      *(uint4*)&Ks[rkv * 72 + ckv + 8] = *(const uint4*)(sk + 8);
      const ushort_t* sv = vt + ((long)(h * 64 + rkv)) * 512 + k0 + ckv;
      *(uint4*)&Vs[rkv * 72 + ckv]     = *(const uint4*)sv;
      *(uint4*)&Vs[rkv * 72 + ckv + 8] = *(const uint4*)(sv + 8); }

    f32x4 acc[2];
    const ushort_t* bp = biasH + ((long)(h * 512 + q0 + wm * 16 + quad * 4)) * 512
                         + k0 + wn * 32 + ln;
#pragma unroll
    for (int t4 = 0; t4 < 2; t4++)
#pragma unroll
      for (int rr = 0; rr < 4; rr++)
        acc[t4][rr] = b2f(bp[(long)rr * 512 + t4 * 16]);

    __syncthreads();                    // K/V ready
#pragma unroll
    for (int s = 0; s < 2; s++) {
      bfrag a = *(const bfrag*)&Qs[(wm * 16 + ln) * 72 + s * 32 + quad * 8];
#pragma unroll
      for (int t4 = 0; t4 < 2; t4++) {
        bfrag b = *(const bfrag*)&Ks[(wn * 32 + t4 * 16 + ln) * 72 + s * 32 + quad * 8];
        acc[t4] = __builtin_amdgcn_mfma_f32_16x16x32_bf16(a, b, acc[t4], 0, 0, 0);
      }
    }

    // wave-private online softmax over this wave's 32 keys
    float mt[4];
#pragma unroll
    for (int rr = 0; rr < 4; rr++) mt[rr] = fmaxf(acc[0][rr], acc[1][rr]);
#pragma unroll
    for (int xm = 1; xm < 16; xm <<= 1)
#pragma unroll
      for (int rr = 0; rr < 4; rr++) mt[rr] = fmaxf(mt[rr], __shfl_xor(mt[rr], xm));
    float al[4];
#pragma unroll
    for (int rr = 0; rr < 4; rr++) {
      float mn = fmaxf(m_[rr], mt[rr]);
      al[rr] = __expf(m_[rr] - mn);
      m_[rr] = mn;
    }
#pragma unroll
    for (int t4 = 0; t4 < 2; t4++)
#pragma unroll
      for (int rr = 0; rr < 4; rr++)
        acc[t4][rr] = __expf(acc[t4][rr] - m_[rr]);
    float rsl[4];
#pragma unroll
    for (int rr = 0; rr < 4; rr++) rsl[rr] = acc[0][rr] + acc[1][rr];
#pragma unroll
    for (int xm = 1; xm < 16; xm <<= 1)
#pragma unroll
      for (int rr = 0; rr < 4; rr++) rsl[rr] += __shfl_xor(rsl[rr], xm);
#pragma unroll
    for (int rr = 0; rr < 4; rr++) l_[rr] = l_[rr] * al[rr] + rsl[rr];
#pragma unroll
    for (int t4 = 0; t4 < 4; t4++)
#pragma unroll
      for (int rr = 0; rr < 4; rr++) Oacc[t4][rr] *= al[rr];

    // P -> wave-private LDS (C-layout -> A-layout round trip)
#pragma unroll
    for (int t4 = 0; t4 < 2; t4++)
#pragma unroll
      for (int rr = 0; rr < 4; rr++)
        Ps[w][(quad * 4 + rr) * 40 + t4 * 16 + ln] = f2b(acc[t4][rr]);
    __builtin_amdgcn_wave_barrier();
    __builtin_amdgcn_s_waitcnt(0xC07F);   // lgkmcnt(0), vm/exp unconstrained
    __builtin_amdgcn_wave_barrier();

    // O += P V (this wave's 32 keys)
    {
      bfrag a = *(const bfrag*)&Ps[w][ln * 40 + quad * 8];
#pragma unroll
      for (int t4 = 0; t4 < 4; t4++) {
        bfrag b = *(const bfrag*)&Vs[(t4 * 16 + ln) * 72 + wn * 32 + quad * 8];
        Oacc[t4] = __builtin_amdgcn_mfma_f32_16x16x32_bf16(a, b, Oacc[t4], 0, 0, 0);
      }
    }
  }

  // merge the two wn key-half streams (flash-decoding style)
  __syncthreads();
  float* ml = (float*)(void*)Ks;    // [4 waves][16 rows][2]
  if (ln == 0)
#pragma unroll
    for (int rr = 0; rr < 4; rr++) {
      ml[(w * 16 + quad * 4 + rr) * 2 + 0] = m_[rr];
      ml[(w * 16 + quad * 4 + rr) * 2 + 1] = l_[rr];
    }
  __syncthreads();
  const int pw_ = wm * 2 + (wn ^ 1);
  float a_self[4];
#pragma unroll
  for (int rr = 0; rr < 4; rr++) {
    float mo = ml[(pw_ * 16 + quad * 4 + rr) * 2 + 0];
    float lo = ml[(pw_ * 16 + quad * 4 + rr) * 2 + 1];
    float mF = fmaxf(m_[rr], mo);
    a_self[rr] = __expf(m_[rr] - mF);
    l_[rr] = l_[rr] * a_self[rr] + lo * __expf(mo - mF);   // final l
  }
  float* Of = (float*)(void*)Vs;    // [2 wm][16 rows][68]
  if (wn == 1) {
#pragma unroll
    for (int t4 = 0; t4 < 4; t4++)
#pragma unroll
      for (int rr = 0; rr < 4; rr++)
        Of[(wm * 16 + quad * 4 + rr) * 68 + t4 * 16 + ln] = Oacc[t4][rr] * a_self[rr];
  }
  __syncthreads();
  if (wn == 0) {
#pragma unroll
    for (int t4 = 0; t4 < 4; t4++) {
#pragma unroll
      for (int rr = 0; rr < 4; rr++) {
        int grow = q0 + wm * 16 + quad * 4 + rr;
        int gcol = h * 64 + t4 * 16 + ln;
        float v = Oacc[t4][rr] * a_self[rr]
                + Of[(wm * 16 + quad * 4 + rr) * 68 + t4 * 16 + ln];
        v /= l_[rr];
        og[(long)grow * 1024 + gcol] = f2b(v * gate[(long)grow * 1024 + gcol]);
      }
    }
  }
}

// ---------------------------------------------------------------------------
// ln2: hln = LN(sbuf) bf16; out = sbuf + b2 (pre-init for mlp2 atomics)
// ---------------------------------------------------------------------------
__global__ __launch_bounds__(256) void ln2(
    const float* __restrict__ sbuf, const float* __restrict__ g,
    const float* __restrict__ b, const float* __restrict__ b2,
    ushort_t* __restrict__ hln, float* __restrict__ out) {
  __shared__ float ps[8];
  int row = blockIdx.x, t = threadIdx.x;
  long base = (long)row * 1024 + t * 4;
  float4 v = *(const float4*)(sbuf + base);
  float4 b2v = *(const float4*)(b2 + t * 4);
  float4 ov; ov.x = v.x + b2v.x; ov.y = v.y + b2v.y; ov.z = v.z + b2v.z; ov.w = v.w + b2v.w;
  *(float4*)(out + base) = ov;
  float s  = v.x + v.y + v.z + v.w;
  float sq = v.x*v.x + v.y*v.y + v.z*v.z + v.w*v.w;
#pragma unroll
  for (int k = 1; k < 64; k <<= 1) { s += __shfl_xor(s, k); sq += __shfl_xor(sq, k); }
  if ((t & 63) == 0) { ps[t >> 6] = s; ps[4 + (t >> 6)] = sq; }
  __syncthreads();
  s  = ps[0] + ps[1] + ps[2] + ps[3];
  sq = ps[4] + ps[5] + ps[6] + ps[7];
  float mu = s * (1.f / 1024.f);
  float rsd = rsqrtf(sq * (1.f / 1024.f) - mu * mu + 1e-5f);
  float4 gv = *(const float4*)(g + t * 4);
  float4 bv = *(const float4*)(b + t * 4);
  uint2 o;
  o.x = pack2((v.x - mu) * rsd * gv.x + bv.x, (v.y - mu) * rsd * gv.y + bv.y);
  o.y = pack2((v.z - mu) * rsd * gv.z + bv.z, (v.w - mu) * rsd * gv.w + bv.w);
  *(uint2*)(hln + base) = o;
}

// ---------------------------------------------------------------------------
extern "C" void kernel_launch(void* const* d_in, const int* in_sizes, int n_in,
                              void* d_out, int out_size, void* d_ws, size_t ws_size,
                              hipStream_t stream) {
  const float* seq    = (const float*)d_in[0];
  const float* pw     = (const float*)d_in[1];
  const float* ln1_g  = (const float*)d_in[3];
  const float* ln1_b  = (const float*)d_in[4];
  const float* proj_w = (const float*)d_in[5];
  const float* g_w    = (const float*)d_in[6];
  const float* g_b    = (const float*)d_in[7];
  const float* o_w    = (const float*)d_in[8];
  const float* o_b    = (const float*)d_in[9];
  const float* p2s_g  = (const float*)d_in[10];
  const float* p2s_b  = (const float*)d_in[11];
  const float* p2s_w  = (const float*)d_in[12];
  const float* mlp_g  = (const float*)d_in[13];
  const float* mlp_bb = (const float*)d_in[14];
  const float* w1     = (const float*)d_in[15];
  const float* b1     = (const float*)d_in[16];
  const float* w2     = (const float*)d_in[17];
  const float* b2     = (const float*)d_in[18];
  float* out = (float*)d_out;
  char* ws = (char*)d_ws;

  ushort_t* biasH = (ushort_t*)(ws + OFF_BIASH);
  ushort_t* ybf   = (ushort_t*)(ws + OFF_Y);
  ushort_t* qs    = (ushort_t*)(ws + OFF_QS);
  ushort_t* ks    = (ushort_t*)(ws + OFF_KS);
  ushort_t* vt    = (ushort_t*)(ws + OFF_VT);
  float* gatebuf  = (float*)(ws + OFF_GATE);
  ushort_t* og    = (ushort_t*)(ws + OFF_OG);
  float* sbuf     = (float*)(ws + OFF_S);
  ushort_t* hln   = (ushort_t*)(ws + OFF_HLN);
  ushort_t* h1    = (ushort_t*)(ws + OFF_H1);
  ushort_t* wpg   = (ushort_t*)(ws + OFF_WPG);
  ushort_t* wo    = (ushort_t*)(ws + OFF_WO);
  ushort_t* w1t   = (ushort_t*)(ws + OFF_W1);
  ushort_t* w2t   = (ushort_t*)(ws + OFF_W2);

  // K1: p2s(MFMA, comb loads) + transposes + ln1 + sbuf init
  mega1<<<7936, 256, 0, stream>>>(pw, p2s_g, p2s_b, p2s_w,
                                  proj_w, g_w, o_w, w1, w2,
                                  seq, ln1_g, ln1_b, o_b,
                                  biasH, wpg, wo, w1t, w2t, ybf, sbuf);
  // K2: merged proj+gate GEMM -> qkv scatter + sigmoid gate (512 blocks)
  gemm64<6><<<dim3(64, 8, 1), 256, 0, stream>>>(ybf, wpg, 1024, 1024, 1024,
                                                g_b, nullptr, nullptr, 0,
                                                qs, ks, vt, gatebuf);
  // K3: flash attention (+bias, +gate) -> og bf16
  flash_attn<<<dim3(16, 16), 256, 0, stream>>>(qs, ks, vt, biasH, gatebuf, og);
  // K4: o_w split-K=4 atomicAdd into sbuf (512 blocks)
  gemm64<7><<<dim3(16, 8, 4), 256, 0, stream>>>(og, wo, 1024, 1024, 256,
                                                nullptr, sbuf, nullptr, 1024,
                                                nullptr, nullptr, nullptr, nullptr);
  // K5: hln = LN(s); out = s + b2
  ln2<<<512, 256, 0, stream>>>(sbuf, mlp_g, mlp_bb, b2, hln, out);
  // K6: h1 = relu(hln @ w1 + b1) bf16 (512 blocks)
  gemm64<3><<<dim3(64, 8, 1), 256, 0, stream>>>(hln, w1t, 1024, 1024, 1024,
                                                b1, nullptr, h1, 4096,
                                                nullptr, nullptr, nullptr, nullptr);
  // K7: mlp2 split-K=4 atomicAdd into out (512 blocks)
  gemm64<7><<<dim3(16, 8, 4), 256, 0, stream>>>(h1, w2t, 4096, 4096, 1024,
                                                nullptr, out, nullptr, 1024,
                                                nullptr, nullptr, nullptr, nullptr);
}